// Round 12
// baseline (435.415 us; speedup 1.0000x reference)
//
#include <hip/hip_runtime.h>
#include <hip/hip_bf16.h>
#include <stdint.h>

#define NE 8
#define DM 1024
#define DH 4096
#define T_TOK 8192
#define NA 16384          // T_TOK * TOP_K assignments
#define BM 128
#define BN 128
#define BK 64
#define MT 20             // tiles per expert (capacity 2560 rows; counts ~2048)

typedef __attribute__((ext_vector_type(8))) short short8;
typedef __attribute__((ext_vector_type(4))) float f32x4;

typedef const __attribute__((address_space(1))) void cas1void;
typedef __attribute__((address_space(3))) void as3void;
// global -> LDS async copy, 16B per lane; LDS dest is wave-uniform base + lane*16
#define GL2L(gp, lp) __builtin_amdgcn_global_load_lds((cas1void*)(uintptr_t)(gp), (as3void*)(uintptr_t)(lp), 16, 0, 0)

__device__ __forceinline__ unsigned short f2bf(float f) {
  union { float f; unsigned u; } v; v.f = f;
  unsigned r = (v.u + 0x7FFFu + ((v.u >> 16) & 1u)) >> 16;
  return (unsigned short)r;
}
__device__ __forceinline__ float b2f(unsigned short u) {
  union { unsigned u; float f; } v; v.u = (unsigned)u << 16; return v.f;
}
// tanh-form GELU (max abs dev from exact erf-GELU ~1e-3, threshold is 6.1e-2)
__device__ __forceinline__ float geluf(float x) {
  float u = 0.7978845608028654f * x * (1.0f + 0.044715f * x * x);
  return x / (1.0f + __expf(-2.0f * u));
}

// ---------------- routing (single block, 1024 threads) ----------------
__global__ void k_route(const int* __restrict__ idx, int* __restrict__ offs,
                        int* __restrict__ btok, int* __restrict__ slotmap) {
  __shared__ int cnt[NE], cur[NE], off_s[NE];
  int tid = threadIdx.x;
  if (tid < NE) { cnt[tid] = 0; cur[tid] = 0; }
  __syncthreads();
  int e_loc[NA / 1024];
#pragma unroll
  for (int i = 0; i < NA / 1024; ++i) {
    int a = i * 1024 + tid;
    e_loc[i] = idx[a];
    atomicAdd(&cnt[e_loc[i]], 1);
  }
  __syncthreads();
  if (tid == 0) {
    int s = 0;
    for (int e = 0; e < NE; ++e) { off_s[e] = s; offs[e] = s; s += cnt[e]; }
    offs[NE] = s;
  }
  __syncthreads();
#pragma unroll
  for (int i = 0; i < NA / 1024; ++i) {
    int a = i * 1024 + tid;
    int e = e_loc[i];
    int pos = off_s[e] + atomicAdd(&cur[e], 1);
    btok[pos] = a >> 1;
    slotmap[a] = pos;
  }
}

// ---------------- fused prep: transposes + x conversion ----------------
// z<NE: wup [DM][DH] -> wupT[DH][DM]; z in [NE,2NE): wdn [DH][DM] -> wdnT[DM][DH];
// z in [2NE, 2NE+4): cvt_x (1024 blocks per z-slice). All families disjoint.
__global__ void k_transpose2(const float* __restrict__ wup, const float* __restrict__ wdn,
                             const float* __restrict__ x,
                             unsigned short* __restrict__ wupT, unsigned short* __restrict__ wdnT,
                             unsigned short* __restrict__ xb) {
  __shared__ float tile[64][65];
  int z = blockIdx.z;
  int tid = threadIdx.x;
  if (z >= 2 * NE) {
    int flat = (z - 2 * NE) * 1024 + blockIdx.y * 64 + blockIdx.x;  // [0,4096)
    int i = (flat * 256 + tid) * 8;
    float4 v0 = *(const float4*)(x + i);
    float4 v1 = *(const float4*)(x + i + 4);
    ushort4 o0, o1;
    o0.x = f2bf(v0.x); o0.y = f2bf(v0.y); o0.z = f2bf(v0.z); o0.w = f2bf(v0.w);
    o1.x = f2bf(v1.x); o1.y = f2bf(v1.y); o1.z = f2bf(v1.z); o1.w = f2bf(v1.w);
    *(ushort4*)(xb + i) = o0;
    *(ushort4*)(xb + i + 4) = o1;
    return;
  }
  const float* src; unsigned short* dst; int C, R, c0, r0;
  if (z < NE) {
    src = wup + (size_t)z * DM * DH; dst = wupT + (size_t)z * DM * DH;
    R = DM; C = DH; c0 = blockIdx.x * 64; r0 = blockIdx.y * 64;
  } else {
    src = wdn + (size_t)(z - NE) * DM * DH; dst = wdnT + (size_t)(z - NE) * DM * DH;
    R = DH; C = DM; c0 = (blockIdx.x & 15) * 64; r0 = (blockIdx.y * 4 + (blockIdx.x >> 4)) * 64;
  }
  int tr = tid >> 4;          // 0..15
  int tc = (tid & 15) * 4;    // 0..60
#pragma unroll
  for (int rr = 0; rr < 64; rr += 16) {
    float4 v = *(const float4*)(src + (size_t)(r0 + tr + rr) * C + c0 + tc);
    tile[tr + rr][tc + 0] = v.x; tile[tr + rr][tc + 1] = v.y;
    tile[tr + rr][tc + 2] = v.z; tile[tr + rr][tc + 3] = v.w;
  }
  __syncthreads();
#pragma unroll
  for (int cc = 0; cc < 64; cc += 16) {
    int oc = tr + cc;
    ushort4 o;
    o.x = f2bf(tile[tc + 0][oc]); o.y = f2bf(tile[tc + 1][oc]);
    o.z = f2bf(tile[tc + 2][oc]); o.w = f2bf(tile[tc + 3][oc]);
    *(ushort4*)(dst + (size_t)(c0 + oc) * R + r0 + tc) = o;
  }
}

// ---------------- m97-style 128x128 GEMM core (multi-block TLP overlap) ----------------
// 256 threads / 4 waves (2Mx2N), 32KB single-buffered LDS, 2 barriers per K-tile.
// Staging: 8 threads per 64-col row; XOR swizzle on 16B granule: gran^(row&7).
template <int NKT>
__device__ __forceinline__ void gemm128(const unsigned short* const (&pA)[4],
                                        const unsigned short* const (&pB)[4],
                                        short* sA, short* sB, int w, int lane,
                                        f32x4 (&acc)[4][4]) {
  int wm = w & 1, wn = w >> 1;
  int lr = lane & 15, lg = lane >> 4;
  int wbase = w << 3;                 // wave's 8-row chunk within each 32-row batch
  int arow = (wm * 64 + lr) * 64;     // A base row offset (elements)
  int brow = (wn * 64 + lr) * 64;
  int swz = ((lr & 7) << 3);          // read-side XOR (in shorts)
#pragma unroll 1
  for (int kt = 0; kt < NKT; ++kt) {
#pragma unroll
    for (int r = 0; r < 4; ++r) {
      GL2L(pA[r] + kt * BK, sA + (r * 32 + wbase) * 64);
      GL2L(pB[r] + kt * BK, sB + (r * 32 + wbase) * 64);
    }
    __syncthreads();                  // compiler drains vmcnt(0): stage landed
#pragma unroll
    for (int kk = 0; kk < 2; ++kk) {
      int co = ((kk << 5) | (lg << 3)) ^ swz;
      short8 av[4], bv[4];
#pragma unroll
      for (int i = 0; i < 4; ++i) av[i] = *(const short8*)&sA[arow + i * 16 * 64 + co];
#pragma unroll
      for (int j = 0; j < 4; ++j) bv[j] = *(const short8*)&sB[brow + j * 16 * 64 + co];
#pragma unroll
      for (int i = 0; i < 4; ++i)
#pragma unroll
        for (int j = 0; j < 4; ++j)
          acc[i][j] = __builtin_amdgcn_mfma_f32_16x16x32_bf16(av[i], bv[j], acc[i][j], 0, 0, 0);
    }
    __syncthreads();                  // all reads done -> next stage may overwrite
  }
}

// ---------------- grouped GEMM kernels ----------------
// k_up bid: e = bid&7 (XCD pin); r = bid>>3: tile = r%MT (fastest), ny slowest
__global__ __launch_bounds__(256, 4) void k_up(
    const unsigned short* __restrict__ xb, const unsigned short* __restrict__ wupT,
    const int* __restrict__ offs, const int* __restrict__ btok,
    unsigned short* __restrict__ h) {
  int e = blockIdx.x & 7;
  int r = blockIdx.x >> 3;
  int tile = r % MT, ny = r / MT;     // ny in [0,32)
  int beg = offs[e], cnt = offs[e + 1] - beg;
  int m0 = tile * BM;
  if (m0 >= cnt) return;
  int n0 = ny * BN;
  __align__(16) __shared__ short sA[BM * BK];
  __align__(16) __shared__ short sB[BN * BK];
  int tid = threadIdx.x;
  int w = tid >> 6, lane = tid & 63;
  int grp = tid >> 3, gran = tid & 7;
  int swcol = ((gran ^ (grp & 7)) << 3);
  const unsigned short* pA[4];
  const unsigned short* pB[4];
#pragma unroll
  for (int rr = 0; rr < 4; ++rr) {
    int row = rr * 32 + grp;
    int tok = btok[beg + min(m0 + row, cnt - 1)];
    pA[rr] = xb + (size_t)tok * DM + swcol;
    pB[rr] = wupT + ((size_t)e * DH + n0 + row) * DM + swcol;
  }
  f32x4 acc[4][4];
#pragma unroll
  for (int i = 0; i < 4; ++i)
#pragma unroll
    for (int j = 0; j < 4; ++j) acc[i][j] = (f32x4){0.f, 0.f, 0.f, 0.f};

  gemm128<DM / BK>(pA, pB, sA, sB, w, lane, acc);

  int wm = w & 1, wn = w >> 1;
  int lr = lane & 15, lg = lane >> 4;
#pragma unroll
  for (int i = 0; i < 4; ++i)
#pragma unroll
    for (int q = 0; q < 4; ++q) {
      int grow = wm * 64 + i * 16 + lg * 4 + q;
      if (m0 + grow < cnt) {
        size_t orow = (size_t)(beg + m0 + grow) * DH + n0;
#pragma unroll
        for (int j = 0; j < 4; ++j) {
          int col = wn * 64 + j * 16 + lr;
          h[orow + col] = f2bf(geluf(acc[i][j][q]));
        }
      }
    }
}

// k_down: split-K x2, NO atomics -- writes ungated bf16 partials dws[ks][slot][DM].
// bid: e = bid&7; r = bid>>3; (ny,ks) fastest, tile slowest.
__global__ __launch_bounds__(256, 4) void k_down(
    const unsigned short* __restrict__ h, const unsigned short* __restrict__ wdnT,
    const int* __restrict__ offs, const int* __restrict__ btok,
    unsigned short* __restrict__ dws) {
  int e = blockIdx.x & 7;
  int r = blockIdx.x >> 3;
  int q2 = r & 15;                    // ny = q2&7, ks = q2>>3
  int ny = q2 & 7, ks = q2 >> 3;
  int tile = r >> 4;
  int beg = offs[e], cnt = offs[e + 1] - beg;
  int m0 = tile * BM;
  if (m0 >= cnt) return;
  int n0 = ny * BN;
  int kbase = ks * (DH / 2);          // 2048 k-elements per split
  __align__(16) __shared__ short sA[BM * BK];
  __align__(16) __shared__ short sB[BN * BK];
  int tid = threadIdx.x;
  int w = tid >> 6, lane = tid & 63;
  int grp = tid >> 3, gran = tid & 7;
  int swcol = ((gran ^ (grp & 7)) << 3);
  const unsigned short* pA[4];
  const unsigned short* pB[4];
#pragma unroll
  for (int rr = 0; rr < 4; ++rr) {
    int row = rr * 32 + grp;
    int slot = beg + min(m0 + row, cnt - 1);
    pA[rr] = h + (size_t)slot * DH + kbase + swcol;
    pB[rr] = wdnT + ((size_t)e * DM + n0 + row) * DH + kbase + swcol;
  }
  f32x4 acc[4][4];
#pragma unroll
  for (int i = 0; i < 4; ++i)
#pragma unroll
    for (int j = 0; j < 4; ++j) acc[i][j] = (f32x4){0.f, 0.f, 0.f, 0.f};

  gemm128<(DH / 2) / BK>(pA, pB, sA, sB, w, lane, acc);

  int wm = w & 1, wn = w >> 1;
  int lr = lane & 15, lg = lane >> 4;
  size_t kofs = (size_t)ks * NA * DM;
#pragma unroll
  for (int i = 0; i < 4; ++i)
#pragma unroll
    for (int q = 0; q < 4; ++q) {
      int grow = wm * 64 + i * 16 + lg * 4 + q;
      if (m0 + grow < cnt) {
        size_t orow = kofs + (size_t)(beg + m0 + grow) * DM + n0;
#pragma unroll
        for (int j = 0; j < 4; ++j) {
          int col = wn * 64 + j * 16 + lr;
          dws[orow + col] = f2bf(acc[i][j][q]);
        }
      }
    }
}

// merge: y[t][c] = p[t,0]*(dws[0][s0][c]+dws[1][s0][c]) + p[t,1]*(dws[0][s1][c]+dws[1][s1][c])
__global__ __launch_bounds__(256) void k_merge(const unsigned short* __restrict__ dws,
                                               const int* __restrict__ slotmap,
                                               const float* __restrict__ p,
                                               float* __restrict__ y) {
  int t = blockIdx.x * 2 + (threadIdx.x >> 7);
  int c0 = (threadIdx.x & 127) * 8;
  int s0 = slotmap[2 * t], s1 = slotmap[2 * t + 1];
  float g0 = p[2 * t], g1 = p[2 * t + 1];
  const size_t KOFS = (size_t)NA * DM;
  short8 a0 = *(const short8*)&dws[(size_t)s0 * DM + c0];
  short8 a1 = *(const short8*)&dws[KOFS + (size_t)s0 * DM + c0];
  short8 b0 = *(const short8*)&dws[(size_t)s1 * DM + c0];
  short8 b1 = *(const short8*)&dws[KOFS + (size_t)s1 * DM + c0];
  float out[8];
#pragma unroll
  for (int k = 0; k < 8; ++k)
    out[k] = g0 * (b2f((unsigned short)a0[k]) + b2f((unsigned short)a1[k])) +
             g1 * (b2f((unsigned short)b0[k]) + b2f((unsigned short)b1[k]));
  float* yp = y + (size_t)t * DM + c0;
  *(float4*)yp = make_float4(out[0], out[1], out[2], out[3]);
  *(float4*)(yp + 4) = make_float4(out[4], out[5], out[6], out[7]);
}

extern "C" void kernel_launch(void* const* d_in, const int* in_sizes, int n_in,
                              void* d_out, int out_size, void* d_ws, size_t ws_size,
                              hipStream_t stream) {
  (void)in_sizes; (void)n_in; (void)ws_size; (void)out_size;
  const float* x   = (const float*)d_in[0];
  const float* p   = (const float*)d_in[1];
  const int*   idx = (const int*)d_in[2];
  const float* wup = (const float*)d_in[3];
  const float* wdn = (const float*)d_in[4];
  float* y = (float*)d_out;
  char* ws = (char*)d_ws;
  int* offs    = (int*)(ws + 128);                // 9 ints
  int* btok    = (int*)(ws + 256);                // 16384 ints (64 KB)
  int* slotmap = (int*)(ws + 256 + 65536);        // 16384 ints (64 KB)
  unsigned short* xb   = (unsigned short*)(ws + 256 + 131072);         // 8192*1024 bf16 (16.8 MB)
  unsigned short* wupT = xb + (size_t)T_TOK * DM;                      // [8][4096][1024] bf16 (67 MB)
  unsigned short* wdnT = wupT + (size_t)NE * DH * DM;                  // [8][1024][4096] bf16 (67 MB)
  unsigned short* h    = wdnT + (size_t)NE * DM * DH;                  // [16384][4096] bf16 (134 MB)
  unsigned short* dws  = wupT;   // overlay: wupT dead after k_up; dws = [2][16384][1024] bf16 (67 MB)

  k_route<<<1, 1024, 0, stream>>>(idx, offs, btok, slotmap);
  k_transpose2<<<dim3(64, 16, 2 * NE + 4), 256, 0, stream>>>(wup, wdn, x, wupT, wdnT, xb);
  k_up<<<NE * MT * 32, 256, 0, stream>>>(xb, wupT, offs, btok, h);       // 5120 blocks
  k_down<<<NE * MT * 16, 256, 0, stream>>>(h, wdnT, offs, btok, dws);    // 2560 blocks
  k_merge<<<T_TOK / 2, 256, 0, stream>>>(dws, slotmap, p, y);            // 4096 blocks
}

// Round 13
// 431.191 us; speedup vs baseline: 1.0098x; 1.0098x over previous
//
#include <hip/hip_runtime.h>
#include <hip/hip_bf16.h>
#include <stdint.h>

#define NE 8
#define DM 1024
#define DH 4096
#define T_TOK 8192
#define NA 16384          // T_TOK * TOP_K assignments
#define BM 128
#define BN 128
#define BK 64
#define MT 20             // tiles per expert (capacity 2560 rows; counts ~2048)

typedef __attribute__((ext_vector_type(8))) short short8;
typedef __attribute__((ext_vector_type(4))) float f32x4;

typedef const __attribute__((address_space(1))) void cas1void;
typedef __attribute__((address_space(3))) void as3void;
// global -> LDS async copy, 16B per lane; LDS dest is wave-uniform base + lane*16
#define GL2L(gp, lp) __builtin_amdgcn_global_load_lds((cas1void*)(uintptr_t)(gp), (as3void*)(uintptr_t)(lp), 16, 0, 0)

// RNE f32->bf16 via the HIP intrinsic: compiler emits v_cvt_pk_bf16_f32 for
// adjacent pairs (m240) -- ~10x fewer VALU ops than the manual bit-twiddle.
__device__ __forceinline__ unsigned short f2bf(float f) {
  __hip_bfloat16 b = __float2bfloat16(f);
  return __builtin_bit_cast(unsigned short, b);
}
__device__ __forceinline__ float b2f(unsigned short u) {
  union { unsigned u; float f; } v; v.u = (unsigned)u << 16; return v.f;
}
// tanh-form GELU, constants folded (max abs dev from exact erf-GELU ~1e-3; thr 6.1e-2)
__device__ __forceinline__ float geluf(float x) {
  float e = __expf(x * (-1.5957691216057308f - 0.071354816222749f * x * x));
  return x / (1.0f + e);
}

// ---------------- routing (single block, 1024 threads) ----------------
__global__ void k_route(const int* __restrict__ idx, int* __restrict__ offs,
                        int* __restrict__ btok, int* __restrict__ slotmap) {
  __shared__ int cnt[NE], cur[NE], off_s[NE];
  int tid = threadIdx.x;
  if (tid < NE) { cnt[tid] = 0; cur[tid] = 0; }
  __syncthreads();
  int e_loc[NA / 1024];
#pragma unroll
  for (int i = 0; i < NA / 1024; ++i) {
    int a = i * 1024 + tid;
    e_loc[i] = idx[a];
    atomicAdd(&cnt[e_loc[i]], 1);
  }
  __syncthreads();
  if (tid == 0) {
    int s = 0;
    for (int e = 0; e < NE; ++e) { off_s[e] = s; offs[e] = s; s += cnt[e]; }
    offs[NE] = s;
  }
  __syncthreads();
#pragma unroll
  for (int i = 0; i < NA / 1024; ++i) {
    int a = i * 1024 + tid;
    int e = e_loc[i];
    int pos = off_s[e] + atomicAdd(&cur[e], 1);
    btok[pos] = a >> 1;
    slotmap[a] = pos;
  }
}

// ---------------- fused prep: transposes + x conversion ----------------
// z<NE: wup [DM][DH] -> wupT[DH][DM]; z in [NE,2NE): wdn [DH][DM] -> wdnT[DM][DH];
// z in [2NE, 2NE+4): cvt_x (1024 blocks per z-slice). All families disjoint.
__global__ void k_transpose2(const float* __restrict__ wup, const float* __restrict__ wdn,
                             const float* __restrict__ x,
                             unsigned short* __restrict__ wupT, unsigned short* __restrict__ wdnT,
                             unsigned short* __restrict__ xb) {
  __shared__ float tile[64][65];
  int z = blockIdx.z;
  int tid = threadIdx.x;
  if (z >= 2 * NE) {
    int flat = (z - 2 * NE) * 1024 + blockIdx.y * 64 + blockIdx.x;  // [0,4096)
    int i = (flat * 256 + tid) * 8;
    float4 v0 = *(const float4*)(x + i);
    float4 v1 = *(const float4*)(x + i + 4);
    ushort4 o0, o1;
    o0.x = f2bf(v0.x); o0.y = f2bf(v0.y); o0.z = f2bf(v0.z); o0.w = f2bf(v0.w);
    o1.x = f2bf(v1.x); o1.y = f2bf(v1.y); o1.z = f2bf(v1.z); o1.w = f2bf(v1.w);
    *(ushort4*)(xb + i) = o0;
    *(ushort4*)(xb + i + 4) = o1;
    return;
  }
  const float* src; unsigned short* dst; int C, R, c0, r0;
  if (z < NE) {
    src = wup + (size_t)z * DM * DH; dst = wupT + (size_t)z * DM * DH;
    R = DM; C = DH; c0 = blockIdx.x * 64; r0 = blockIdx.y * 64;
  } else {
    src = wdn + (size_t)(z - NE) * DM * DH; dst = wdnT + (size_t)(z - NE) * DM * DH;
    R = DH; C = DM; c0 = (blockIdx.x & 15) * 64; r0 = (blockIdx.y * 4 + (blockIdx.x >> 4)) * 64;
  }
  int tr = tid >> 4;          // 0..15
  int tc = (tid & 15) * 4;    // 0..60
#pragma unroll
  for (int rr = 0; rr < 64; rr += 16) {
    float4 v = *(const float4*)(src + (size_t)(r0 + tr + rr) * C + c0 + tc);
    tile[tr + rr][tc + 0] = v.x; tile[tr + rr][tc + 1] = v.y;
    tile[tr + rr][tc + 2] = v.z; tile[tr + rr][tc + 3] = v.w;
  }
  __syncthreads();
#pragma unroll
  for (int cc = 0; cc < 64; cc += 16) {
    int oc = tr + cc;
    ushort4 o;
    o.x = f2bf(tile[tc + 0][oc]); o.y = f2bf(tile[tc + 1][oc]);
    o.z = f2bf(tile[tc + 2][oc]); o.w = f2bf(tile[tc + 3][oc]);
    *(ushort4*)(dst + (size_t)(c0 + oc) * R + r0 + tc) = o;
  }
}

// ---------------- m97-style 128x128 GEMM core (multi-block TLP overlap) ----------------
// 256 threads / 4 waves (2Mx2N), 32KB single-buffered LDS, 2 barriers per K-tile.
// Staging: 8 threads per 64-col row; XOR swizzle on 16B granule: gran^(row&7).
template <int NKT>
__device__ __forceinline__ void gemm128(const unsigned short* const (&pA)[4],
                                        const unsigned short* const (&pB)[4],
                                        short* sA, short* sB, int w, int lane,
                                        f32x4 (&acc)[4][4]) {
  int wm = w & 1, wn = w >> 1;
  int lr = lane & 15, lg = lane >> 4;
  int wbase = w << 3;                 // wave's 8-row chunk within each 32-row batch
  int arow = (wm * 64 + lr) * 64;     // A base row offset (elements)
  int brow = (wn * 64 + lr) * 64;
  int swz = ((lr & 7) << 3);          // read-side XOR (in shorts)
#pragma unroll 1
  for (int kt = 0; kt < NKT; ++kt) {
#pragma unroll
    for (int r = 0; r < 4; ++r) {
      GL2L(pA[r] + kt * BK, sA + (r * 32 + wbase) * 64);
      GL2L(pB[r] + kt * BK, sB + (r * 32 + wbase) * 64);
    }
    __syncthreads();                  // compiler drains vmcnt(0): stage landed
#pragma unroll
    for (int kk = 0; kk < 2; ++kk) {
      int co = ((kk << 5) | (lg << 3)) ^ swz;
      short8 av[4], bv[4];
#pragma unroll
      for (int i = 0; i < 4; ++i) av[i] = *(const short8*)&sA[arow + i * 16 * 64 + co];
#pragma unroll
      for (int j = 0; j < 4; ++j) bv[j] = *(const short8*)&sB[brow + j * 16 * 64 + co];
#pragma unroll
      for (int i = 0; i < 4; ++i)
#pragma unroll
        for (int j = 0; j < 4; ++j)
          acc[i][j] = __builtin_amdgcn_mfma_f32_16x16x32_bf16(av[i], bv[j], acc[i][j], 0, 0, 0);
    }
    __syncthreads();                  // all reads done -> next stage may overwrite
  }
}

// ---------------- grouped GEMM kernels ----------------
// k_up bid: e = bid&7 (XCD pin); r = bid>>3: tile = r%MT (fastest), ny slowest
__global__ __launch_bounds__(256, 4) void k_up(
    const unsigned short* __restrict__ xb, const unsigned short* __restrict__ wupT,
    const int* __restrict__ offs, const int* __restrict__ btok,
    unsigned short* __restrict__ h) {
  int e = blockIdx.x & 7;
  int r = blockIdx.x >> 3;
  int tile = r % MT, ny = r / MT;     // ny in [0,32)
  int beg = offs[e], cnt = offs[e + 1] - beg;
  int m0 = tile * BM;
  if (m0 >= cnt) return;
  int n0 = ny * BN;
  __align__(16) __shared__ short sA[BM * BK];
  __align__(16) __shared__ short sB[BN * BK];
  int tid = threadIdx.x;
  int w = tid >> 6, lane = tid & 63;
  int grp = tid >> 3, gran = tid & 7;
  int swcol = ((gran ^ (grp & 7)) << 3);
  const unsigned short* pA[4];
  const unsigned short* pB[4];
#pragma unroll
  for (int rr = 0; rr < 4; ++rr) {
    int row = rr * 32 + grp;
    int tok = btok[beg + min(m0 + row, cnt - 1)];
    pA[rr] = xb + (size_t)tok * DM + swcol;
    pB[rr] = wupT + ((size_t)e * DH + n0 + row) * DM + swcol;
  }
  f32x4 acc[4][4];
#pragma unroll
  for (int i = 0; i < 4; ++i)
#pragma unroll
    for (int j = 0; j < 4; ++j) acc[i][j] = (f32x4){0.f, 0.f, 0.f, 0.f};

  gemm128<DM / BK>(pA, pB, sA, sB, w, lane, acc);

  int wm = w & 1, wn = w >> 1;
  int lr = lane & 15, lg = lane >> 4;
#pragma unroll
  for (int i = 0; i < 4; ++i)
#pragma unroll
    for (int q = 0; q < 4; ++q) {
      int grow = wm * 64 + i * 16 + lg * 4 + q;
      if (m0 + grow < cnt) {
        size_t orow = (size_t)(beg + m0 + grow) * DH + n0;
#pragma unroll
        for (int j = 0; j < 4; ++j) {
          int col = wn * 64 + j * 16 + lr;
          h[orow + col] = f2bf(geluf(acc[i][j][q]));
        }
      }
    }
}

// k_down: split-K x2, NO atomics -- writes ungated bf16 partials dws[ks][slot][DM].
// bid: e = bid&7; r = bid>>3; (ny,ks) fastest, tile slowest.
__global__ __launch_bounds__(256, 4) void k_down(
    const unsigned short* __restrict__ h, const unsigned short* __restrict__ wdnT,
    const int* __restrict__ offs, const int* __restrict__ btok,
    unsigned short* __restrict__ dws) {
  int e = blockIdx.x & 7;
  int r = blockIdx.x >> 3;
  int q2 = r & 15;                    // ny = q2&7, ks = q2>>3
  int ny = q2 & 7, ks = q2 >> 3;
  int tile = r >> 4;
  int beg = offs[e], cnt = offs[e + 1] - beg;
  int m0 = tile * BM;
  if (m0 >= cnt) return;
  int n0 = ny * BN;
  int kbase = ks * (DH / 2);          // 2048 k-elements per split
  __align__(16) __shared__ short sA[BM * BK];
  __align__(16) __shared__ short sB[BN * BK];
  int tid = threadIdx.x;
  int w = tid >> 6, lane = tid & 63;
  int grp = tid >> 3, gran = tid & 7;
  int swcol = ((gran ^ (grp & 7)) << 3);
  const unsigned short* pA[4];
  const unsigned short* pB[4];
#pragma unroll
  for (int rr = 0; rr < 4; ++rr) {
    int row = rr * 32 + grp;
    int slot = beg + min(m0 + row, cnt - 1);
    pA[rr] = h + (size_t)slot * DH + kbase + swcol;
    pB[rr] = wdnT + ((size_t)e * DM + n0 + row) * DH + kbase + swcol;
  }
  f32x4 acc[4][4];
#pragma unroll
  for (int i = 0; i < 4; ++i)
#pragma unroll
    for (int j = 0; j < 4; ++j) acc[i][j] = (f32x4){0.f, 0.f, 0.f, 0.f};

  gemm128<(DH / 2) / BK>(pA, pB, sA, sB, w, lane, acc);

  int wm = w & 1, wn = w >> 1;
  int lr = lane & 15, lg = lane >> 4;
  size_t kofs = (size_t)ks * NA * DM;
#pragma unroll
  for (int i = 0; i < 4; ++i)
#pragma unroll
    for (int q = 0; q < 4; ++q) {
      int grow = wm * 64 + i * 16 + lg * 4 + q;
      if (m0 + grow < cnt) {
        size_t orow = kofs + (size_t)(beg + m0 + grow) * DM + n0;
#pragma unroll
        for (int j = 0; j < 4; ++j) {
          int col = wn * 64 + j * 16 + lr;
          dws[orow + col] = f2bf(acc[i][j][q]);
        }
      }
    }
}

// merge: y[t][c] = p[t,0]*(dws[0][s0][c]+dws[1][s0][c]) + p[t,1]*(dws[0][s1][c]+dws[1][s1][c])
__global__ __launch_bounds__(256) void k_merge(const unsigned short* __restrict__ dws,
                                               const int* __restrict__ slotmap,
                                               const float* __restrict__ p,
                                               float* __restrict__ y) {
  int t = blockIdx.x * 2 + (threadIdx.x >> 7);
  int c0 = (threadIdx.x & 127) * 8;
  int s0 = slotmap[2 * t], s1 = slotmap[2 * t + 1];
  float g0 = p[2 * t], g1 = p[2 * t + 1];
  const size_t KOFS = (size_t)NA * DM;
  short8 a0 = *(const short8*)&dws[(size_t)s0 * DM + c0];
  short8 a1 = *(const short8*)&dws[KOFS + (size_t)s0 * DM + c0];
  short8 b0 = *(const short8*)&dws[(size_t)s1 * DM + c0];
  short8 b1 = *(const short8*)&dws[KOFS + (size_t)s1 * DM + c0];
  float out[8];
#pragma unroll
  for (int k = 0; k < 8; ++k)
    out[k] = g0 * (b2f((unsigned short)a0[k]) + b2f((unsigned short)a1[k])) +
             g1 * (b2f((unsigned short)b0[k]) + b2f((unsigned short)b1[k]));
  float* yp = y + (size_t)t * DM + c0;
  *(float4*)yp = make_float4(out[0], out[1], out[2], out[3]);
  *(float4*)(yp + 4) = make_float4(out[4], out[5], out[6], out[7]);
}

extern "C" void kernel_launch(void* const* d_in, const int* in_sizes, int n_in,
                              void* d_out, int out_size, void* d_ws, size_t ws_size,
                              hipStream_t stream) {
  (void)in_sizes; (void)n_in; (void)ws_size; (void)out_size;
  const float* x   = (const float*)d_in[0];
  const float* p   = (const float*)d_in[1];
  const int*   idx = (const int*)d_in[2];
  const float* wup = (const float*)d_in[3];
  const float* wdn = (const float*)d_in[4];
  float* y = (float*)d_out;
  char* ws = (char*)d_ws;
  int* offs    = (int*)(ws + 128);                // 9 ints
  int* btok    = (int*)(ws + 256);                // 16384 ints (64 KB)
  int* slotmap = (int*)(ws + 256 + 65536);        // 16384 ints (64 KB)
  unsigned short* xb   = (unsigned short*)(ws + 256 + 131072);         // 8192*1024 bf16 (16.8 MB)
  unsigned short* wupT = xb + (size_t)T_TOK * DM;                      // [8][4096][1024] bf16 (67 MB)
  unsigned short* wdnT = wupT + (size_t)NE * DH * DM;                  // [8][1024][4096] bf16 (67 MB)
  unsigned short* h    = wdnT + (size_t)NE * DM * DH;                  // [16384][4096] bf16 (134 MB)
  unsigned short* dws  = wupT;   // overlay: wupT dead after k_up; dws = [2][16384][1024] bf16 (67 MB)

  k_route<<<1, 1024, 0, stream>>>(idx, offs, btok, slotmap);
  k_transpose2<<<dim3(64, 16, 2 * NE + 4), 256, 0, stream>>>(wup, wdn, x, wupT, wdnT, xb);
  k_up<<<NE * MT * 32, 256, 0, stream>>>(xb, wupT, offs, btok, h);       // 5120 blocks
  k_down<<<NE * MT * 16, 256, 0, stream>>>(h, wdnT, offs, btok, dws);    // 2560 blocks
  k_merge<<<T_TOK / 2, 256, 0, stream>>>(dws, slotmap, p, y);            // 4096 blocks
}